// Round 1
// baseline (115.203 us; speedup 1.0000x reference)
//
#include <hip/hip_runtime.h>
#include <hip/hip_fp16.h>

typedef _Float16 f16;
typedef _Float16 f16x8 __attribute__((ext_vector_type(8)));
typedef float f32x16 __attribute__((ext_vector_type(16)));

#define NEGV (-1e30f)

constexpr int T_    = 8192;
constexpr int BATCH = 4;
constexpr int D_    = 1024;   // K
constexpr int C_    = 128;
constexpr int ROWS  = BATCH * T_;   // 32768
constexpr int BM    = 128;
constexpr int BK    = 64;
constexpr int KT    = D_ / BK;      // 16
constexpr int NWG   = ROWS / BM;    // 256
constexpr int NTHR  = 512;

// ws layout: [0,1MB) swizzled f16 weights (per kt: 64KB tile, byte = col*128 + ((2k)^((col&7)<<4)))
//            [1MB,2MB) boundary floats: bound[g][2][4][128]  (mat0=Cb, mat1=Zb)
#define BOUND_OFF (1u << 20)

__device__ __forceinline__ void gload_lds16(const void* g, void* l) {
  __builtin_amdgcn_global_load_lds(
      (const __attribute__((address_space(1))) void*)g,
      (__attribute__((address_space(3))) void*)l, 16, 0, 0);
}

// ---------------- prep: weight convert+swizzle, boundary rows ----------------
__global__ __launch_bounds__(256) void tc_prep(
    const float* __restrict__ H,
    const float* __restrict__ Wakv, const float* __restrict__ Wbkv,
    const float* __restrict__ Waz,  const float* __restrict__ Wbz,
    unsigned char* __restrict__ ws)
{
  __shared__ float hrow[4][1024];
  const int b = blockIdx.x, t = threadIdx.x;
  if (b < NWG) {
    // boundary rows for WG g=b: global rows b*128-4 .. b*128-1 (prev block of local block 0)
    float* bound = (float*)(ws + BOUND_OFF) + (long long)b * 1024;
    const int j = t & 127, half = t >> 7;   // half 0 -> Cb, 1 -> Zb
    if ((b & 63) == 0) {
      // batch boundary (or g==0): no previous block
      const float vz = half ? NEGV : 0.f;
#pragma unroll
      for (int m = 0; m < 4; ++m) bound[half*512 + m*128 + j] = vz;
    } else {
      const long long R0 = (long long)b * BM - 4;
      for (int i = t; i < 4096; i += 256) hrow[i >> 10][i & 1023] = H[R0 * D_ + i];
      __syncthreads();
      const float* Wm = half ? Wbz : Wbkv;
      float a0 = 0.f, a1 = 0.f, a2 = 0.f, a3 = 0.f;
#pragma unroll 4
      for (int k = 0; k < 1024; ++k) {
        float wv = Wm[k*128 + j];
        a0 += hrow[0][k] * wv; a1 += hrow[1][k] * wv;
        a2 += hrow[2][k] * wv; a3 += hrow[3][k] * wv;
      }
      bound[half*512 + 0*128 + j] = a0;
      bound[half*512 + 1*128 + j] = a1;
      bound[half*512 + 2*128 + j] = a2;
      bound[half*512 + 3*128 + j] = a3;
    }
  } else {
    // weights: one 16B unit (8 f16 along k) per thread
    const int u   = (b - NWG) * 256 + t;       // 0..65535
    const int kt  = u >> 12;
    const int rem = u & 4095;
    const int k8  = rem >> 9;                  // 0..7
    const int col = rem & 511;                 // 0..511
    const int mat = col >> 7, j = col & 127;
    const float* Wm = (mat == 0) ? Wakv : (mat == 1) ? Wbkv : (mat == 2) ? Waz : Wbz;
    f16x8 v;
#pragma unroll
    for (int e = 0; e < 8; ++e) v[e] = (f16)Wm[(kt*64 + k8*8 + e)*128 + j];
    *(f16x8*)(ws + (size_t)kt*65536 + col*128 + ((k8*16) ^ ((col & 7) << 4))) = v;
  }
}

// ---------------- main fused kernel ----------------
// per WG: 128 rows x 512 cols (Ca|Cb|Za|Zb), f16 MFMA 32x32x16, fused softmax epilogue
__global__ __launch_bounds__(NTHR, 2) void tc_main(
    const float* __restrict__ H,
    const float* __restrict__ Ba,
    const float* __restrict__ Bbb,
    const unsigned char* __restrict__ ws,
    float* __restrict__ out)
{
  __shared__ __align__(16) unsigned char lds[16384 + 2*65536];   // 144 KB
  unsigned char* sA  = lds;
  unsigned char* sB0 = lds + 16384;
  unsigned char* sB1 = lds + 16384 + 65536;

  const int tid  = threadIdx.x;
  const int w    = tid >> 6;
  const int lane = tid & 63;
  const int g    = blockIdx.x;
  const long long R0 = (long long)g * BM;

  f32x16 acc[2][4];
#pragma unroll
  for (int i = 0; i < 2; ++i)
#pragma unroll
    for (int jq = 0; jq < 4; ++jq)
#pragma unroll
      for (int e = 0; e < 16; ++e) acc[i][jq][e] = 0.f;

  // --- A staging indices: thread -> (row, 16-float chunk)
  const int ar   = tid >> 2;          // 0..127
  const int akq  = tid & 3;           // 0..3
  const float* aptr = H + (R0 + ar) * D_ + akq * 16;
  const int abase = ar * 128;
  const int aswz  = (ar & 7) << 4;

  // --- compute-phase per-wave constants
  const int whalf = w >> 2;           // row half (0/1)
  const int jpos  = w & 3;            // 32-col j-strip within each projection group
  const int mrow  = lane & 31;
  const int kq2   = (lane >> 5) * 16; // byte offset of this lane's 8 f16 within 32B k-pair
  const int axor  = (mrow & 7) << 4;
  const int arow0 = (whalf*64 + mrow) * 128;
  const int arow1 = arow0 + 32*128;
  const int jb    = (jpos*32 + mrow) * 128;

  float4 areg[4];

  // prologue: issue B(0), load A(0)
#pragma unroll
  for (int r = 0; r < 8; ++r)
    gload_lds16(ws + (size_t)0*65536 + w*1024 + r*8192 + lane*16, sB0 + w*1024 + r*8192);
  {
    const float4* p = (const float4*)aptr;
    areg[0] = p[0]; areg[1] = p[1]; areg[2] = p[2]; areg[3] = p[3];
  }

  for (int kt = 0; kt < KT; ++kt) {
    // convert + swizzled ds_write A(kt)   (implicit vmcnt wait on areg)
    {
      f16x8 v0, v1;
      const float* af = (const float*)areg;
#pragma unroll
      for (int e = 0; e < 8; ++e) { v0[e] = (f16)af[e]; v1[e] = (f16)af[8 + e]; }
      *(f16x8*)(sA + abase + ((akq*32)      ^ aswz)) = v0;
      *(f16x8*)(sA + abase + ((akq*32 + 16) ^ aswz)) = v1;
    }
    // issue B(kt+1) into other buffer (kt==KT-1 issues a harmless wrap tile)
    const int ktn = (kt + 1) & (KT - 1);
    unsigned char* sBn = ((kt + 1) & 1) ? sB1 : sB0;
#pragma unroll
    for (int r = 0; r < 8; ++r)
      gload_lds16(ws + (size_t)ktn*65536 + w*1024 + r*8192 + lane*16, sBn + w*1024 + r*8192);

    // barrier 1: ds_writes visible; keep the 8 fresh B loads in flight
    __builtin_amdgcn_sched_barrier(0);
    asm volatile("s_waitcnt vmcnt(8) lgkmcnt(0)" ::: "memory");
    __builtin_amdgcn_sched_barrier(0);
    __builtin_amdgcn_s_barrier();
    __builtin_amdgcn_sched_barrier(0);

    // prefetch A(kt+1) regs (latency hides under MFMA)
    {
      const float4* p = (const float4*)(aptr + ktn * 64);
      areg[0] = p[0]; areg[1] = p[1]; areg[2] = p[2]; areg[3] = p[3];
    }

    const unsigned char* sBc = (kt & 1) ? sB1 : sB0;
#pragma unroll
    for (int kf = 0; kf < 4; ++kf) {
      const int ko = ((kf*32 + kq2) ^ axor);
      f16x8 a0 = *(const f16x8*)(sA + arow0 + ko);
      f16x8 a1 = *(const f16x8*)(sA + arow1 + ko);
#pragma unroll
      for (int gr = 0; gr < 4; ++gr) {
        f16x8 bv = *(const f16x8*)(sBc + gr*16384 + jb + ko);
        acc[0][gr] = __builtin_amdgcn_mfma_f32_32x32x16_f16(a0, bv, acc[0][gr], 0, 0, 0);
        acc[1][gr] = __builtin_amdgcn_mfma_f32_32x32x16_f16(a1, bv, acc[1][gr], 0, 0, 0);
      }
    }

    // barrier 2: protect sA before next iteration's ds_write
    __builtin_amdgcn_sched_barrier(0);
    __builtin_amdgcn_s_barrier();
    __builtin_amdgcn_sched_barrier(0);
  }

  // drain the wrap-issued gll before reusing LDS
  asm volatile("s_waitcnt vmcnt(0)" ::: "memory");
  __builtin_amdgcn_s_barrier();

  // ---------------- epilogue ----------------
  float* eCb = (float*)lds;               // [128][128]
  float* eZb = (float*)(lds + 65536);     // [128][128]
  const int jj = jpos*32 + mrow;          // 0..127 channel
  const int h  = lane >> 5;

#pragma unroll
  for (int rf = 0; rf < 2; ++rf)
#pragma unroll
    for (int r = 0; r < 16; ++r) {
      const int row = whalf*64 + rf*32 + (r & 3) + 8*(r >> 2) + 4*h;
      eCb[row*128 + jj] = acc[rf][1][r];
      eZb[row*128 + jj] = acc[rf][3][r];
    }
  __syncthreads();

  float bav[4], bbv[4];
#pragma unroll
  for (int m = 0; m < 4; ++m) { bav[m] = Ba[m*128 + jj]; bbv[m] = Bbb[m*128 + jj]; }
  const float* bound = (const float*)(ws + BOUND_OFF) + (long long)g * 1024;

#pragma unroll
  for (int rf = 0; rf < 2; ++rf)
#pragma unroll
    for (int q = 0; q < 4; ++q) {
      const int bf = 2*q + h;                 // block within 32-row frag
      const int bl = whalf*16 + rf*8 + bf;    // local block 0..31
      float za[4], ca[4], zb[4], cb[4];
#pragma unroll
      for (int m = 0; m < 4; ++m) {
        za[m] = acc[rf][2][q*4 + m] + bav[m];
        ca[m] = acc[rf][0][q*4 + m];
      }
      if (bl == 0) {
#pragma unroll
        for (int m = 0; m < 4; ++m) {
          cb[m] = bound[m*128 + jj];
          zb[m] = bound[512 + m*128 + jj] + bbv[m];
        }
      } else {
#pragma unroll
        for (int m = 0; m < 4; ++m) {
          const int pr = bl*4 - 4 + m;
          cb[m] = eCb[pr*128 + jj];
          zb[m] = eZb[pr*128 + jj] + bbv[m];
        }
      }
      float mx = za[0];
#pragma unroll
      for (int m = 1; m < 4; ++m) mx = fmaxf(mx, za[m]);
#pragma unroll
      for (int m = 0; m < 4; ++m) mx = fmaxf(mx, zb[m]);
      float s = 0.f, o = 0.f;
#pragma unroll
      for (int m = 0; m < 4; ++m) {
        const float ea = __expf(za[m] - mx);
        const float eb = __expf(zb[m] - mx);
        s += ea + eb;
        o += ea*ca[m] + eb*cb[m];
      }
      out[((long long)g*32 + bl)*128 + jj] = o / s;
    }
}

extern "C" void kernel_launch(void* const* d_in, const int* in_sizes, int n_in,
                              void* d_out, int out_size, void* d_ws, size_t ws_size,
                              hipStream_t stream) {
  const float* H    = (const float*)d_in[0];
  const float* Wakv = (const float*)d_in[1];
  const float* Wbkv = (const float*)d_in[2];
  const float* Waz  = (const float*)d_in[3];
  const float* Wbz  = (const float*)d_in[4];
  const float* Ba   = (const float*)d_in[5];
  const float* Bbb  = (const float*)d_in[6];
  float* out        = (float*)d_out;
  unsigned char* ws = (unsigned char*)d_ws;

  tc_prep<<<NWG + 256, 256, 0, stream>>>(H, Wakv, Wbkv, Waz, Wbz, ws);
  tc_main<<<NWG, NTHR, 0, stream>>>(H, Ba, Bbb, ws, out);
}

// Round 2
// 65.697 us; speedup vs baseline: 1.7536x; 1.7536x over previous
//
#include <hip/hip_runtime.h>
#include <hip/hip_fp16.h>

typedef _Float16 f16;
typedef _Float16 f16x8 __attribute__((ext_vector_type(8)));
typedef float f32x16 __attribute__((ext_vector_type(16)));

#define NEGV (-1e30f)

constexpr int T_    = 8192;
constexpr int BATCH = 4;
constexpr int D_    = 1024;   // K
constexpr int C_    = 128;
constexpr int ROWS  = BATCH * T_;   // 32768
constexpr int BM    = 128;
constexpr int BK    = 64;
constexpr int KT    = D_ / BK;      // 16
constexpr int NWG   = ROWS / BM;    // 256
constexpr int NTHR  = 512;

// ws layout: [0,1MB) swizzled f16 weights (per kt: 64KB tile, byte = col*128 + ((2k)^((col&7)<<4)))
//            [1MB,2MB) boundary floats: bound[g][2][4][128]  (half0=Cb, half1=Zb)
#define BOUND_OFF (1u << 20)

__device__ __forceinline__ void gload_lds16(const void* g, void* l) {
  __builtin_amdgcn_global_load_lds(
      (const __attribute__((address_space(1))) void*)g,
      (__attribute__((address_space(3))) void*)l, 16, 0, 0);
}

// ---------------- prep: weight convert+swizzle, boundary rows ----------------
// blocks [0, NWG): boundary rows for WG g (k-split across 8 chunks, LDS reduce)
// blocks [NWG, NWG+64): weight convert+swizzle (1024 thr * 64 = 65536 units)
__global__ __launch_bounds__(1024) void tc_prep(
    const float* __restrict__ H,
    const float* __restrict__ Wakv, const float* __restrict__ Wbkv,
    const float* __restrict__ Waz,  const float* __restrict__ Wbz,
    unsigned char* __restrict__ ws)
{
  const int b = blockIdx.x, t = threadIdx.x;
  if (b < NWG) {
    float* bound = (float*)(ws + BOUND_OFF) + (long long)b * 1024;
    if ((b & 63) == 0) {
      // batch boundary (incl. g==0): no previous block -> Cb=0, Zb=NEG
      bound[t] = (t < 512) ? 0.f : NEGV;
      return;
    }
    __shared__ float hrow[4][1024];        // 16 KB
    __shared__ float part[8][8][128];      // 32 KB  [kc][half*4+m][j]
    const long long R0 = (long long)b * BM - 4;
    for (int i = t; i < 4096; i += 1024) hrow[i >> 10][i & 1023] = H[R0 * D_ + i];
    __syncthreads();

    const int j  = t & 127;
    const int kc = t >> 7;                 // 0..7, constant per wave
    const int k0 = kc * 128;
    float acc[2][4] = {{0.f,0.f,0.f,0.f},{0.f,0.f,0.f,0.f}};
#pragma unroll 4
    for (int k = k0; k < k0 + 128; ++k) {
      const float w0 = Wbkv[k*128 + j];
      const float w1 = Wbz [k*128 + j];
#pragma unroll
      for (int m = 0; m < 4; ++m) {
        const float hv = hrow[m][k];       // wave-uniform -> LDS broadcast
        acc[0][m] += hv * w0;
        acc[1][m] += hv * w1;
      }
    }
#pragma unroll
    for (int half = 0; half < 2; ++half)
#pragma unroll
      for (int m = 0; m < 4; ++m) part[kc][half*4 + m][j] = acc[half][m];
    __syncthreads();

    // 1024 outputs; thread t owns bound[t] = bound[half*512 + m*128 + j]
    {
      const int half = t >> 9, rm = (t >> 7) & 3, jj = t & 127;
      float s = 0.f;
#pragma unroll
      for (int kk = 0; kk < 8; ++kk) s += part[kk][half*4 + rm][jj];
      bound[t] = s;
    }
  } else {
    // weights: one 16B unit (8 f16 along k) per thread
    const int u   = (b - NWG) * 1024 + t;      // 0..65535
    const int kt  = u >> 12;
    const int rem = u & 4095;
    const int k8  = rem >> 9;                  // 0..7
    const int col = rem & 511;                 // 0..511
    const int mat = col >> 7, j = col & 127;
    const float* Wm = (mat == 0) ? Wakv : (mat == 1) ? Wbkv : (mat == 2) ? Waz : Wbz;
    f16x8 v;
#pragma unroll
    for (int e = 0; e < 8; ++e) v[e] = (f16)Wm[(kt*64 + k8*8 + e)*128 + j];
    *(f16x8*)(ws + (size_t)kt*65536 + col*128 + ((k8*16) ^ ((col & 7) << 4))) = v;
  }
}

// ---------------- main fused kernel ----------------
// per WG: 128 rows x 512 cols (Ca|Cb|Za|Zb), f16 MFMA 32x32x16, fused softmax epilogue
__global__ __launch_bounds__(NTHR, 2) void tc_main(
    const float* __restrict__ H,
    const float* __restrict__ Ba,
    const float* __restrict__ Bbb,
    const unsigned char* __restrict__ ws,
    float* __restrict__ out)
{
  __shared__ __align__(16) unsigned char lds[16384 + 2*65536];   // 144 KB
  unsigned char* sA  = lds;
  unsigned char* sB0 = lds + 16384;
  unsigned char* sB1 = lds + 16384 + 65536;

  const int tid  = threadIdx.x;
  const int w    = tid >> 6;
  const int lane = tid & 63;
  const int g    = blockIdx.x;
  const long long R0 = (long long)g * BM;

  f32x16 acc[2][4];
#pragma unroll
  for (int i = 0; i < 2; ++i)
#pragma unroll
    for (int jq = 0; jq < 4; ++jq)
#pragma unroll
      for (int e = 0; e < 16; ++e) acc[i][jq][e] = 0.f;

  // --- A staging indices: thread -> (row, 16-float chunk)
  const int ar   = tid >> 2;          // 0..127
  const int akq  = tid & 3;           // 0..3
  const float* aptr = H + (R0 + ar) * D_ + akq * 16;
  const int abase = ar * 128;
  const int aswz  = (ar & 7) << 4;

  // --- compute-phase per-wave constants
  const int whalf = w >> 2;           // row half (0/1)
  const int jpos  = w & 3;            // 32-col j-strip within each projection group
  const int mrow  = lane & 31;
  const int kq2   = (lane >> 5) * 16; // byte offset of this lane's 8 f16 within 32B k-pair
  const int axor  = (mrow & 7) << 4;
  const int arow0 = (whalf*64 + mrow) * 128;
  const int arow1 = arow0 + 32*128;
  const int jb    = (jpos*32 + mrow) * 128;

  float4 areg[4];

  // prologue: issue B(0), load A(0)
#pragma unroll
  for (int r = 0; r < 8; ++r)
    gload_lds16(ws + (size_t)0*65536 + w*1024 + r*8192 + lane*16, sB0 + w*1024 + r*8192);
  {
    const float4* p = (const float4*)aptr;
    areg[0] = p[0]; areg[1] = p[1]; areg[2] = p[2]; areg[3] = p[3];
  }

  for (int kt = 0; kt < KT; ++kt) {
    // convert + swizzled ds_write A(kt)   (implicit vmcnt wait on areg)
    {
      f16x8 v0, v1;
      const float* af = (const float*)areg;
#pragma unroll
      for (int e = 0; e < 8; ++e) { v0[e] = (f16)af[e]; v1[e] = (f16)af[8 + e]; }
      *(f16x8*)(sA + abase + ((akq*32)      ^ aswz)) = v0;
      *(f16x8*)(sA + abase + ((akq*32 + 16) ^ aswz)) = v1;
    }
    // issue B(kt+1) into other buffer (kt==KT-1 issues a harmless wrap tile)
    const int ktn = (kt + 1) & (KT - 1);
    unsigned char* sBn = ((kt + 1) & 1) ? sB1 : sB0;
#pragma unroll
    for (int r = 0; r < 8; ++r)
      gload_lds16(ws + (size_t)ktn*65536 + w*1024 + r*8192 + lane*16, sBn + w*1024 + r*8192);

    // barrier 1: ds_writes visible; keep the 8 fresh B loads in flight
    __builtin_amdgcn_sched_barrier(0);
    asm volatile("s_waitcnt vmcnt(8) lgkmcnt(0)" ::: "memory");
    __builtin_amdgcn_sched_barrier(0);
    __builtin_amdgcn_s_barrier();
    __builtin_amdgcn_sched_barrier(0);

    // prefetch A(kt+1) regs (latency hides under MFMA)
    {
      const float4* p = (const float4*)(aptr + ktn * 64);
      areg[0] = p[0]; areg[1] = p[1]; areg[2] = p[2]; areg[3] = p[3];
    }

    const unsigned char* sBc = (kt & 1) ? sB1 : sB0;
#pragma unroll
    for (int kf = 0; kf < 4; ++kf) {
      const int ko = ((kf*32 + kq2) ^ axor);
      f16x8 a0 = *(const f16x8*)(sA + arow0 + ko);
      f16x8 a1 = *(const f16x8*)(sA + arow1 + ko);
#pragma unroll
      for (int gr = 0; gr < 4; ++gr) {
        f16x8 bv = *(const f16x8*)(sBc + gr*16384 + jb + ko);
        acc[0][gr] = __builtin_amdgcn_mfma_f32_32x32x16_f16(a0, bv, acc[0][gr], 0, 0, 0);
        acc[1][gr] = __builtin_amdgcn_mfma_f32_32x32x16_f16(a1, bv, acc[1][gr], 0, 0, 0);
      }
    }

    // barrier 2: protect sA before next iteration's ds_write
    __builtin_amdgcn_sched_barrier(0);
    __builtin_amdgcn_s_barrier();
    __builtin_amdgcn_sched_barrier(0);
  }

  // drain the wrap-issued gll before reusing LDS
  asm volatile("s_waitcnt vmcnt(0)" ::: "memory");
  __builtin_amdgcn_s_barrier();

  // ---------------- epilogue ----------------
  float* eCb = (float*)lds;               // [128][128]
  float* eZb = (float*)(lds + 65536);     // [128][128]
  const int jj = jpos*32 + mrow;          // 0..127 channel
  const int h  = lane >> 5;

#pragma unroll
  for (int rf = 0; rf < 2; ++rf)
#pragma unroll
    for (int r = 0; r < 16; ++r) {
      const int row = whalf*64 + rf*32 + (r & 3) + 8*(r >> 2) + 4*h;
      eCb[row*128 + jj] = acc[rf][1][r];
      eZb[row*128 + jj] = acc[rf][3][r];
    }
  __syncthreads();

  float bav[4], bbv[4];
#pragma unroll
  for (int m = 0; m < 4; ++m) { bav[m] = Ba[m*128 + jj]; bbv[m] = Bbb[m*128 + jj]; }
  const float* bound = (const float*)(ws + BOUND_OFF) + (long long)g * 1024;

#pragma unroll
  for (int rf = 0; rf < 2; ++rf)
#pragma unroll
    for (int q = 0; q < 4; ++q) {
      const int bf = 2*q + h;                 // block within 32-row frag
      const int bl = whalf*16 + rf*8 + bf;    // local block 0..31
      float za[4], ca[4], zb[4], cb[4];
#pragma unroll
      for (int m = 0; m < 4; ++m) {
        za[m] = acc[rf][2][q*4 + m] + bav[m];
        ca[m] = acc[rf][0][q*4 + m];
      }
      if (bl == 0) {
#pragma unroll
        for (int m = 0; m < 4; ++m) {
          cb[m] = bound[m*128 + jj];
          zb[m] = bound[512 + m*128 + jj] + bbv[m];
        }
      } else {
#pragma unroll
        for (int m = 0; m < 4; ++m) {
          const int pr = bl*4 - 4 + m;
          cb[m] = eCb[pr*128 + jj];
          zb[m] = eZb[pr*128 + jj] + bbv[m];
        }
      }
      float mx = za[0];
#pragma unroll
      for (int m = 1; m < 4; ++m) mx = fmaxf(mx, za[m]);
#pragma unroll
      for (int m = 0; m < 4; ++m) mx = fmaxf(mx, zb[m]);
      float s = 0.f, o = 0.f;
#pragma unroll
      for (int m = 0; m < 4; ++m) {
        const float ea = __expf(za[m] - mx);
        const float eb = __expf(zb[m] - mx);
        s += ea + eb;
        o += ea*ca[m] + eb*cb[m];
      }
      out[((long long)g*32 + bl)*128 + jj] = o / s;
    }
}

extern "C" void kernel_launch(void* const* d_in, const int* in_sizes, int n_in,
                              void* d_out, int out_size, void* d_ws, size_t ws_size,
                              hipStream_t stream) {
  const float* H    = (const float*)d_in[0];
  const float* Wakv = (const float*)d_in[1];
  const float* Wbkv = (const float*)d_in[2];
  const float* Waz  = (const float*)d_in[3];
  const float* Wbz  = (const float*)d_in[4];
  const float* Ba   = (const float*)d_in[5];
  const float* Bbb  = (const float*)d_in[6];
  float* out        = (float*)d_out;
  unsigned char* ws = (unsigned char*)d_ws;

  tc_prep<<<NWG + 64, 1024, 0, stream>>>(H, Wakv, Wbkv, Waz, Wbz, ws);
  tc_main<<<NWG, NTHR, 0, stream>>>(H, Ba, Bbb, ws, out);
}